// Round 15
// baseline (267.465 us; speedup 1.0000x reference)
//
#include <hip/hip_runtime.h>
#include <math.h>

// Problem constants (match reference)
constexpr int B = 128;
constexpr int N = 512;
constexpr int DEG = 8;
constexpr int D = 128;
constexpr int E = B * N * DEG;         // 524288
constexpr int NN = B * N;              // 65536 total nodes
constexpr int K1 = 410;                // ceil(0.8*512)
constexpr int K2 = 328;                // ceil(0.8*410)
constexpr int CAP = 32;                // padded-list capacity (max deg ~23)
constexpr int AST = 36;                // As/Bs LDS stride (shorts)
constexpr int LST = 33;                // lidx/lwk LDS stride (slots)

typedef __attribute__((ext_vector_type(8))) short short8;
typedef __attribute__((ext_vector_type(4))) float f32x4;

__device__ __forceinline__ unsigned short f2bf(float f) {
    unsigned int u = __float_as_uint(f);
    unsigned int r = (u + 0x7fffu + ((u >> 16) & 1u)) >> 16;   // RNE
    return (unsigned short)r;
}
__device__ __forceinline__ float bf2f(unsigned short h) {
    return __uint_as_float(((unsigned int)h) << 16);
}

// ---------------------------------------------------------------------------
// Weight prep, TILED TRANSPOSE: W[k][n] fp32 -> W^T[n][k] bf16 hi/lo.
// Round-15 fix: the old version wrote the transpose with 262144 scattered
// 2-byte stores (each wave-store touched 64 cache lines). Now: 64 blocks x
// one 32x32 tile each -- coalesced 16B row loads, hi/lo split into an LDS
// tile [n][k] (+1 pad), then CONTIGUOUS 8B transposed stores (64B per
// n-row segment). Also zeroes ccnt (int4 per thread). Layout unchanged.
// ---------------------------------------------------------------------------
__global__ __launch_bounds__(256) void k_prepw(const float* __restrict__ W0,
                                               const float* __restrict__ W1,
                                               const float* __restrict__ W2,
                                               const float* __restrict__ W3,
                                               unsigned short* __restrict__ wt,
                                               int* __restrict__ ccnt) {
    __shared__ unsigned short tH[32][33], tL[32][33];
    const float* Ws[4] = {W0, W1, W2, W3};
    const int bidx = blockIdx.x;               // 0..63
    const int m = bidx >> 4;                   // matrix 0..3
    const int tile = bidx & 15;                // 16 tiles of 32x32
    const int tk = (tile >> 2) * 32;           // k-origin
    const int tn = (tile & 3) * 32;            // n-origin
    const int t = threadIdx.x;
    // zero ccnt: 64 blocks x 256 threads x int4 = 65536 ints
    *(int4*)&ccnt[(bidx * 256 + t) * 4] = make_int4(0, 0, 0, 0);
    // load 32x32 fp32 tile (coalesced 16B/thread) + split into LDS transposed
    {
        const int lk = t >> 3;                 // 0..31 (k within tile)
        const int ln0 = (t & 7) * 4;           // 0..28 (n within tile)
        float4 v = *(const float4*)&Ws[m][(size_t)(tk + lk) * 128 + tn + ln0];
        float vv[4] = {v.x, v.y, v.z, v.w};
        #pragma unroll
        for (int u = 0; u < 4; ++u) {
            unsigned short h = f2bf(vv[u]);
            tH[ln0 + u][lk] = h;
            tL[ln0 + u][lk] = f2bf(vv[u] - bf2f(h));
        }
    }
    __syncthreads();
    // write transposed: thread owns (n, 4 consecutive k) -> contiguous 8B
    {
        const int on = t >> 3;                 // 0..31 (n within tile)
        const int ok0 = (t & 7) * 4;           // 0..28 (k within tile)
        unsigned short* dH = wt + (size_t)m * 32768;
        unsigned short* dL = dH + 16384;
        unsigned short hbuf[4], lbuf[4];
        #pragma unroll
        for (int u = 0; u < 4; ++u) { hbuf[u] = tH[on][ok0 + u]; lbuf[u] = tL[on][ok0 + u]; }
        *(int2*)&dH[(size_t)(tn + on) * 128 + tk + ok0] = *(int2*)hbuf;
        *(int2*)&dL[(size_t)(tn + on) * 128 + tk + ok0] = *(int2*)lbuf;
    }
}

// ---------------------------------------------------------------------------
// Edge-parallel count+scatter (arrival order racy -- canonicalized below).
// ---------------------------------------------------------------------------
__global__ __launch_bounds__(256) void k_count(const int* __restrict__ ei,
                                               int* __restrict__ ccnt,
                                               int* __restrict__ csrcp) {
    const int e = blockIdx.x * 256 + threadIdx.x;
    const int s = ei[e];
    const int d = ei[E + e];
    const int pos = atomicAdd(&ccnt[d], 1);
    if (pos < CAP) csrcp[(size_t)d * CAP + pos] = s;
}

// ---------------------------------------------------------------------------
// Canonicalize: per-node register bitonic sort ascending (pads = INT_MAX).
// Sorted order is a pure function of the input -> bit-identical replays.
// ---------------------------------------------------------------------------
__global__ __launch_bounds__(256) void k_sortpad(int* __restrict__ ccnt,
                                                 int* __restrict__ csrcp) {
    const int n = blockIdx.x * 256 + threadIdx.x;
    const int deg = min(ccnt[n], CAP);
    int a[CAP];
    #pragma unroll
    for (int j = 0; j < CAP / 4; ++j)
        *(int4*)&a[4 * j] = *(const int4*)&csrcp[(size_t)n * CAP + 4 * j];
    #pragma unroll
    for (int k = 0; k < CAP; ++k)
        if (k >= deg) a[k] = 0x7fffffff;
    #pragma unroll
    for (int k = 2; k <= CAP; k <<= 1) {
        #pragma unroll
        for (int j = k >> 1; j > 0; j >>= 1) {
            #pragma unroll
            for (int i = 0; i < CAP; ++i) {
                const int l = i ^ j;
                if (l > i) {
                    const bool dir = ((i & k) == 0);
                    int x = a[i], y = a[l];
                    if ((x > y) == dir) { a[i] = y; a[l] = x; }
                }
            }
        }
    }
    #pragma unroll
    for (int j = 0; j < CAP / 4; ++j)
        *(int4*)&csrcp[(size_t)n * CAP + 4 * j] =
            make_int4(a[4 * j], a[4 * j + 1], a[4 * j + 2], a[4 * j + 3]);
}

// ---------------------------------------------------------------------------
// FUSED gather + MFMA conv GEMM (bf16 hi/lo split, 3-product):
//   out = relu( (feat.*gate) @ W0 + agg(feat.*gate) @ W1 + bias )
//   sun[row] = out[row,:].pvec
// 512 blocks (128 graphs x 4 row-chunks, XCD-swizzled). 512 thr = 8 waves,
// each 32x64 via 2x4 MFMA tiles. Round-12 proven config: B staged through
// LDS, launch_bounds(512,4), VGPR 64, no spills, ~54us/dispatch.
// ---------------------------------------------------------------------------
__global__ __launch_bounds__(512, 4) void k_fgemm(const float* __restrict__ feat,
                                                  const float* __restrict__ gate,
                                                  const int* __restrict__ ccnt,
                                                  const int* __restrict__ csrcp,
                                                  const unsigned short* __restrict__ W0t,
                                                  const unsigned short* __restrict__ W1t,
                                                  const float* __restrict__ bias,
                                                  const float* __restrict__ pvec,
                                                  float* __restrict__ out,
                                                  float* __restrict__ sun) {
    __shared__ unsigned short AsBuf[2 * 128 * AST];    // AsH | AsL (18 KB)
    __shared__ unsigned short BsH[128 * AST], BsL[128 * AST];
    __shared__ unsigned short lidx[128 * LST];         // 8.4 KB
    __shared__ float lwk[128 * LST];                   // 16.9 KB
    __shared__ int ldeg[128];
    unsigned short* AsH = AsBuf;
    unsigned short* AsL = AsBuf + 128 * AST;
    float* red = (float*)AsBuf;                        // aliased epilogue buffer
    const int bid = blockIdx.x;
    const int xcd = bid & 7, j = bid >> 3;             // j: 0..63
    const int g = (j & 15) * 8 + xcd;                  // graph, fixed per xcd
    const int chunkRow = j >> 4;                       // 0..3
    const int r0 = g * N + chunkRow * 128;
    const int t = threadIdx.x;
    const int w = t >> 6, lane = t & 63;
    const int lr = lane & 15, kg = (lane >> 4) * 8;
    const int wm = (w >> 1) * 32, wn = (w & 1) * 64;   // wave tile 32x64
    const int arow = t >> 2, kpart = (t & 3) * 8;      // staging: 4 thr/row
    const int node = r0 + arow;
    const float ga = gate ? gate[node] : 1.0f;

    // --- stage neighbor lists once: thread (arow, q) owns slots q*8..q*8+7
    {
        const int q = t & 3;
        const int deg = min(ccnt[node], CAP);
        if (q == 0) ldeg[arow] = deg;
        int4 i0 = *(const int4*)&csrcp[(size_t)node * CAP + q * 8];
        int4 i1 = *(const int4*)&csrcp[(size_t)node * CAP + q * 8 + 4];
        int ids[8] = {i0.x, i0.y, i0.z, i0.w, i1.x, i1.y, i1.z, i1.w};
        #pragma unroll
        for (int u = 0; u < 8; ++u) {
            const int slot = q * 8 + u;
            lidx[arow * LST + slot] = (unsigned short)ids[u];
            float wv = 0.f;
            if (slot < deg) wv = gate ? gate[ids[u]] : 1.0f;
            lwk[arow * LST + slot] = wv;
        }
    }
    __syncthreads();

    f32x4 acc[2][4];
    #pragma unroll
    for (int mt = 0; mt < 2; ++mt)
        #pragma unroll
        for (int nt = 0; nt < 4; ++nt)
            acc[mt][nt] = (f32x4)(0.f);

    for (int phase = 0; phase < 2; ++phase) {
        const unsigned short* WH = phase ? W1t : W0t;
        const unsigned short* WL = WH + 16384;
        for (int c = 0; c < 4; ++c) {
            const int k0 = c * 32;
            __syncthreads();                 // previous chunk fully consumed
            // --- A source: 8 fp32 for (row=arow, k=k0+kpart..+8)
            float vals[8];
            if (phase == 0) {
                float4 a0 = *(const float4*)&feat[(size_t)node * D + k0 + kpart];
                float4 a1 = *(const float4*)&feat[(size_t)node * D + k0 + kpart + 4];
                vals[0] = a0.x * ga; vals[1] = a0.y * ga; vals[2] = a0.z * ga; vals[3] = a0.w * ga;
                vals[4] = a1.x * ga; vals[5] = a1.y * ga; vals[6] = a1.z * ga; vals[7] = a1.w * ga;
            } else {
                #pragma unroll
                for (int u = 0; u < 8; ++u) vals[u] = 0.f;
                const int deg = ldeg[arow];
                for (int k = 0; k < deg; ++k) {       // sorted -> deterministic
                    const int ix = lidx[arow * LST + k];
                    const float wv = lwk[arow * LST + k];
                    float4 v0 = *(const float4*)&feat[(size_t)ix * D + k0 + kpart];
                    float4 v1 = *(const float4*)&feat[(size_t)ix * D + k0 + kpart + 4];
                    vals[0] = fmaf(v0.x, wv, vals[0]); vals[1] = fmaf(v0.y, wv, vals[1]);
                    vals[2] = fmaf(v0.z, wv, vals[2]); vals[3] = fmaf(v0.w, wv, vals[3]);
                    vals[4] = fmaf(v1.x, wv, vals[4]); vals[5] = fmaf(v1.y, wv, vals[5]);
                    vals[6] = fmaf(v1.z, wv, vals[6]); vals[7] = fmaf(v1.w, wv, vals[7]);
                }
            }
            // --- split to hi/lo bf16, write LDS [row][k] stride 36 (2x int2)
            {
                unsigned int ph[4], pl[4];
                #pragma unroll
                for (int jj = 0; jj < 4; ++jj) {
                    unsigned int h0 = f2bf(vals[2 * jj]), h1 = f2bf(vals[2 * jj + 1]);
                    ph[jj] = h0 | (h1 << 16);
                    unsigned int l0 = f2bf(vals[2 * jj] - bf2f((unsigned short)h0));
                    unsigned int l1 = f2bf(vals[2 * jj + 1] - bf2f((unsigned short)h1));
                    pl[jj] = l0 | (l1 << 16);
                }
                *(int2*)&AsH[arow * AST + kpart]     = make_int2(ph[0], ph[1]);
                *(int2*)&AsH[arow * AST + kpart + 4] = make_int2(ph[2], ph[3]);
                *(int2*)&AsL[arow * AST + kpart]     = make_int2(pl[0], pl[1]);
                *(int2*)&AsL[arow * AST + kpart + 4] = make_int2(pl[2], pl[3]);
            }
            // --- B stage: copy pre-split W^T[n][k] chunk
            {
                int4 bh = *(const int4*)&WH[arow * 128 + k0 + kpart];
                int4 bl = *(const int4*)&WL[arow * 128 + k0 + kpart];
                *(int2*)&BsH[arow * AST + kpart]     = make_int2(bh.x, bh.y);
                *(int2*)&BsH[arow * AST + kpart + 4] = make_int2(bh.z, bh.w);
                *(int2*)&BsL[arow * AST + kpart]     = make_int2(bl.x, bl.y);
                *(int2*)&BsL[arow * AST + kpart + 4] = make_int2(bl.z, bl.w);
            }
            __syncthreads();
            // --- fragments (2x b64 each) + MFMA
            short8 aH[2], aL[2], bH[4], bL[4];
            #pragma unroll
            for (int mt = 0; mt < 2; ++mt) {
                const int ra = (wm + mt * 16 + lr) * AST + kg;
                ((int2*)&aH[mt])[0] = *(const int2*)&AsH[ra];
                ((int2*)&aH[mt])[1] = *(const int2*)&AsH[ra + 4];
                ((int2*)&aL[mt])[0] = *(const int2*)&AsL[ra];
                ((int2*)&aL[mt])[1] = *(const int2*)&AsL[ra + 4];
            }
            #pragma unroll
            for (int nt = 0; nt < 4; ++nt) {
                const int rb = (wn + nt * 16 + lr) * AST + kg;
                ((int2*)&bH[nt])[0] = *(const int2*)&BsH[rb];
                ((int2*)&bH[nt])[1] = *(const int2*)&BsH[rb + 4];
                ((int2*)&bL[nt])[0] = *(const int2*)&BsL[rb];
                ((int2*)&bL[nt])[1] = *(const int2*)&BsL[rb + 4];
            }
            #pragma unroll
            for (int mt = 0; mt < 2; ++mt)
                #pragma unroll
                for (int nt = 0; nt < 4; ++nt) {
                    acc[mt][nt] = __builtin_amdgcn_mfma_f32_16x16x32_bf16(aH[mt], bH[nt], acc[mt][nt], 0, 0, 0);
                    acc[mt][nt] = __builtin_amdgcn_mfma_f32_16x16x32_bf16(aH[mt], bL[nt], acc[mt][nt], 0, 0, 0);
                    acc[mt][nt] = __builtin_amdgcn_mfma_f32_16x16x32_bf16(aL[mt], bH[nt], acc[mt][nt], 0, 0, 0);
                }
        }
    }
    __syncthreads();                          // A staging dead -> red may alias
    // --- Epilogue: bias + relu + store + score partials
    float bb[4], pv[4];
    #pragma unroll
    for (int nt = 0; nt < 4; ++nt) {
        bb[nt] = bias[wn + nt * 16 + lr];
        pv[nt] = pvec[wn + nt * 16 + lr];
    }
    #pragma unroll
    for (int mt = 0; mt < 2; ++mt) {
        #pragma unroll
        for (int r = 0; r < 4; ++r) {
            const int rowl = wm + mt * 16 + (lane >> 4) * 4 + r;
            const int row = r0 + rowl;
            float part = 0.f;
            #pragma unroll
            for (int nt = 0; nt < 4; ++nt) {
                float v = acc[mt][nt][r] + bb[nt];
                v = fmaxf(v, 0.f);
                out[(size_t)row * D + wn + nt * 16 + lr] = v;
                part = fmaf(v, pv[nt], part);
            }
            red[rowl * 33 + (w & 1) * 16 + lr] = part;   // unique slot per lane
        }
    }
    __syncthreads();
    if (t < 128) {
        float s = 0.f;
        #pragma unroll
        for (int jj = 0; jj < 32; ++jj) s += red[t * 33 + jj];
        sun[r0 + t] = s;
    }
}

// ---------------------------------------------------------------------------
// Fused per-graph TopK + readout, 2 blocks per graph (feature halves).
// ---------------------------------------------------------------------------
__global__ __launch_bounds__(1024) void k_topk_readout(const float* __restrict__ sun,
                                                       const float* __restrict__ p,
                                                       const float* __restrict__ prevmask,
                                                       int K, float invK,
                                                       const float* __restrict__ h,
                                                       float* __restrict__ gate,
                                                       float* __restrict__ mask,
                                                       float* __restrict__ xout) {
    __shared__ float ls[512];
    __shared__ float lg[512];
    __shared__ float lm[512];
    __shared__ float red[128];
    __shared__ float smax[16][64];
    __shared__ float ssum[16][64];
    __shared__ float norm_s;
    const int bid = blockIdx.x;
    const int g = bid >> 1, half = bid & 1;
    const int t = threadIdx.x;
    if (t < 512) {
        const int n = g * N + t;
        float s = sun[n];
        if (prevmask && prevmask[n] == 0.0f) s = -INFINITY;
        ls[t] = s;
    }
    if (t < 128) { float pvv = p[t]; red[t] = pvv * pvv; }
    __syncthreads();
    if (t < 64) red[t] += red[t + 64];
    __syncthreads();
    if (t < 32) red[t] += red[t + 32];
    __syncthreads();
    if (t == 0) {
        float s = 0.f;
        #pragma unroll
        for (int i = 0; i < 32; ++i) s += red[i];
        norm_s = sqrtf(s);
    }
    __syncthreads();
    if (t < 512) {
        const float s = ls[t];
        int cnt = 0;
        for (int jj = 0; jj < 512; ++jj) {
            float sj = ls[jj];
            cnt += (sj > s || (sj == s && jj < t)) ? 1 : 0;
        }
        const bool keep = cnt < K;
        const float gv = keep ? tanhf(s / norm_s) : 0.0f;
        const float mv = keep ? 1.0f : 0.0f;
        lg[t] = gv; lm[t] = mv;
        gate[g * N + t] = gv; mask[g * N + t] = mv;
    }
    __syncthreads();
    const int f = half * 64 + (t & 63), sub = t >> 6;   // 16 subsets x 64 feats
    float vmax = -INFINITY, vsum = 0.f;
    for (int nl = sub; nl < N; nl += 16) {
        const float v = h[(size_t)(g * N + nl) * D + f] * lg[nl];
        vsum += v;
        if (lm[nl] != 0.f) vmax = fmaxf(vmax, v);
    }
    smax[sub][t & 63] = vmax;
    ssum[sub][t & 63] = vsum;
    __syncthreads();
    if (t < 64) {
        float m = smax[0][t], s = ssum[0][t];
        #pragma unroll
        for (int k = 1; k < 16; ++k) { m = fmaxf(m, smax[k][t]); s += ssum[k][t]; }
        xout[g * 256 + half * 64 + t] = m;
        xout[g * 256 + 128 + half * 64 + t] = s * invK;
    }
}

// ---------------------------------------------------------------------------
// MLP head. One block (128 threads) per graph.
// ---------------------------------------------------------------------------
__global__ __launch_bounds__(128) void k_mlp(const float* __restrict__ X1,
                                             const float* __restrict__ X2,
                                             const float* __restrict__ lw1,
                                             const float* __restrict__ lb1,
                                             const float* __restrict__ lw2,
                                             const float* __restrict__ lb2,
                                             const float* __restrict__ lw3,
                                             const float* __restrict__ lb3,
                                             float* __restrict__ out) {
    __shared__ float z[256];
    __shared__ float o1[128];
    __shared__ float o2p[64];
    const int g = blockIdx.x, t = threadIdx.x;
    z[t] = X1[g * 256 + t] + X2[g * 256 + t];
    z[t + 128] = X1[g * 256 + 128 + t] + X2[g * 256 + 128 + t];
    __syncthreads();
    float a = lb1[t];
    for (int i = 0; i < 256; ++i) a = fmaf(z[i], lw1[i * 128 + t], a);
    o1[t] = fmaxf(a, 0.f);
    __syncthreads();
    if (t < 64) {
        float b = lb2[t];
        for (int i = 0; i < 128; ++i) b = fmaf(o1[i], lw2[i * 64 + t], b);
        o2p[t] = fmaxf(b, 0.f) * lw3[t];
    }
    __syncthreads();
    if (t == 0) {
        float sacc = lb3[0];
        for (int i = 0; i < 64; ++i) sacc += o2p[i];
        out[g] = 1.f / (1.f + expf(-sacc));
    }
}

// ---------------------------------------------------------------------------
extern "C" void kernel_launch(void* const* d_in, const int* in_sizes, int n_in,
                              void* d_out, int out_size, void* d_ws, size_t ws_size,
                              hipStream_t stream) {
    const float* x    = (const float*)d_in[0];
    const int*   ei   = (const int*)d_in[1];
    const float* W1r  = (const float*)d_in[2];
    const float* W1n  = (const float*)d_in[3];
    const float* b1   = (const float*)d_in[4];
    const float* p1   = (const float*)d_in[5];
    const float* W2r  = (const float*)d_in[6];
    const float* W2n  = (const float*)d_in[7];
    const float* b2   = (const float*)d_in[8];
    const float* p2   = (const float*)d_in[9];
    const float* lw1  = (const float*)d_in[10];
    const float* lb1  = (const float*)d_in[11];
    const float* lw2  = (const float*)d_in[12];
    const float* lb2  = (const float*)d_in[13];
    const float* lw3  = (const float*)d_in[14];
    const float* lb3  = (const float*)d_in[15];
    float* out = (float*)d_out;

    // Workspace layout (~78 MB total)
    char* w = (char*)d_ws;
    float* h1  = (float*)w; w += (size_t)NN * D * 4;
    float* h2  = (float*)w; w += (size_t)NN * D * 4;
    int* ccnt  = (int*)w;   w += (size_t)NN * 4;
    int* csrcp = (int*)w;   w += (size_t)NN * CAP * 4;      // 8 MB
    unsigned short* wt = (unsigned short*)w; w += (size_t)4 * 2 * 16384 * 2;  // 4 mats x hi/lo
    float* sun = (float*)w; w += (size_t)NN * 4;
    float* g1  = (float*)w; w += (size_t)NN * 4;
    float* m1  = (float*)w; w += (size_t)NN * 4;
    float* g2  = (float*)w; w += (size_t)NN * 4;
    float* m2  = (float*)w; w += (size_t)NN * 4;
    float* X1  = (float*)w; w += (size_t)B * 256 * 4;
    float* X2  = (float*)w; w += (size_t)B * 256 * 4;

    const unsigned short* wt1r = wt;                 // slot 0: W1r
    const unsigned short* wt1n = wt + 1 * 32768;     // slot 1: W1n
    const unsigned short* wt2r = wt + 2 * 32768;     // slot 2: W2r
    const unsigned short* wt2n = wt + 3 * 32768;     // slot 3: W2n

    // One-time prep: tiled weight transpose (+ ccnt zeroing), edge scatter,
    // canonical sort
    k_prepw<<<64, 256, 0, stream>>>(W1r, W1n, W2r, W2n, wt, ccnt);
    k_count<<<E / 256, 256, 0, stream>>>(ei, ccnt, csrcp);
    k_sortpad<<<NN / 256, 256, 0, stream>>>(ccnt, csrcp);

    // conv1: h1 = relu(x@W1r + agg(x)@W1n + b1); s1 = h1.p1
    k_fgemm<<<512, 512, 0, stream>>>(x, nullptr, ccnt, csrcp, wt1r, wt1n, b1, p1, h1, sun);
    k_topk_readout<<<2 * B, 1024, 0, stream>>>(sun, p1, nullptr, K1, 1.0f / (float)K1, h1, g1, m1, X1);

    // conv2: h2 = relu((h1.*g1)@W2r + agg(h1.*g1)@W2n + b2); s2 = h2.p2
    k_fgemm<<<512, 512, 0, stream>>>(h1, g1, ccnt, csrcp, wt2r, wt2n, b2, p2, h2, sun);
    k_topk_readout<<<2 * B, 1024, 0, stream>>>(sun, p2, m1, K2, 1.0f / (float)K2, h2, g2, m2, X2);

    // MLP head
    k_mlp<<<B, 128, 0, stream>>>(X1, X2, lw1, lb1, lw2, lb2, lw3, lb3, out);
}

// Round 16
// 262.071 us; speedup vs baseline: 1.0206x; 1.0206x over previous
//
#include <hip/hip_runtime.h>
#include <math.h>

// Problem constants (match reference)
constexpr int B = 128;
constexpr int N = 512;
constexpr int DEG = 8;
constexpr int D = 128;
constexpr int E = B * N * DEG;         // 524288
constexpr int NN = B * N;              // 65536 total nodes
constexpr int K1 = 410;                // ceil(0.8*512)
constexpr int K2 = 328;                // ceil(0.8*410)
constexpr int CAP = 32;                // padded-list capacity (max deg ~23)
constexpr int AST = 36;                // As/Bs LDS stride (shorts)
constexpr int LST = 33;                // lidx/lwk LDS stride (slots)

typedef __attribute__((ext_vector_type(8))) short short8;
typedef __attribute__((ext_vector_type(4))) float f32x4;

__device__ __forceinline__ unsigned short f2bf(float f) {
    unsigned int u = __float_as_uint(f);
    unsigned int r = (u + 0x7fffu + ((u >> 16) & 1u)) >> 16;   // RNE
    return (unsigned short)r;
}
__device__ __forceinline__ float bf2f(unsigned short h) {
    return __uint_as_float(((unsigned int)h) << 16);
}

// ---------------------------------------------------------------------------
// Weight prep, tiled transpose: W[k][n] fp32 -> W^T[n][k] bf16 hi/lo.
// 64 blocks x one 32x32 tile; coalesced loads, LDS transpose, contiguous
// 8B stores. Also zeroes ccnt (int4 per thread).
// ---------------------------------------------------------------------------
__global__ __launch_bounds__(256) void k_prepw(const float* __restrict__ W0,
                                               const float* __restrict__ W1,
                                               const float* __restrict__ W2,
                                               const float* __restrict__ W3,
                                               unsigned short* __restrict__ wt,
                                               int* __restrict__ ccnt) {
    __shared__ unsigned short tH[32][33], tL[32][33];
    const float* Ws[4] = {W0, W1, W2, W3};
    const int bidx = blockIdx.x;               // 0..63
    const int m = bidx >> 4;                   // matrix 0..3
    const int tile = bidx & 15;                // 16 tiles of 32x32
    const int tk = (tile >> 2) * 32;           // k-origin
    const int tn = (tile & 3) * 32;            // n-origin
    const int t = threadIdx.x;
    *(int4*)&ccnt[(bidx * 256 + t) * 4] = make_int4(0, 0, 0, 0);
    {
        const int lk = t >> 3;                 // 0..31 (k within tile)
        const int ln0 = (t & 7) * 4;           // 0..28 (n within tile)
        float4 v = *(const float4*)&Ws[m][(size_t)(tk + lk) * 128 + tn + ln0];
        float vv[4] = {v.x, v.y, v.z, v.w};
        #pragma unroll
        for (int u = 0; u < 4; ++u) {
            unsigned short h = f2bf(vv[u]);
            tH[ln0 + u][lk] = h;
            tL[ln0 + u][lk] = f2bf(vv[u] - bf2f(h));
        }
    }
    __syncthreads();
    {
        const int on = t >> 3;                 // 0..31 (n within tile)
        const int ok0 = (t & 7) * 4;           // 0..28 (k within tile)
        unsigned short* dH = wt + (size_t)m * 32768;
        unsigned short* dL = dH + 16384;
        unsigned short hbuf[4], lbuf[4];
        #pragma unroll
        for (int u = 0; u < 4; ++u) { hbuf[u] = tH[on][ok0 + u]; lbuf[u] = tL[on][ok0 + u]; }
        *(int2*)&dH[(size_t)(tn + on) * 128 + tk + ok0] = *(int2*)hbuf;
        *(int2*)&dL[(size_t)(tn + on) * 128 + tk + ok0] = *(int2*)lbuf;
    }
}

// ---------------------------------------------------------------------------
// Edge-parallel count+scatter (arrival order racy -- canonicalized below).
// ---------------------------------------------------------------------------
__global__ __launch_bounds__(256) void k_count(const int* __restrict__ ei,
                                               int* __restrict__ ccnt,
                                               int* __restrict__ csrcp) {
    const int e = blockIdx.x * 256 + threadIdx.x;
    const int s = ei[e];
    const int d = ei[E + e];
    const int pos = atomicAdd(&ccnt[d], 1);
    if (pos < CAP) csrcp[(size_t)d * CAP + pos] = s;
}

// ---------------------------------------------------------------------------
// Canonicalize: per-node register bitonic sort ascending (pads = INT_MAX).
// Sorted order is a pure function of the input -> bit-identical replays.
// ---------------------------------------------------------------------------
__global__ __launch_bounds__(256) void k_sortpad(int* __restrict__ ccnt,
                                                 int* __restrict__ csrcp) {
    const int n = blockIdx.x * 256 + threadIdx.x;
    const int deg = min(ccnt[n], CAP);
    int a[CAP];
    #pragma unroll
    for (int j = 0; j < CAP / 4; ++j)
        *(int4*)&a[4 * j] = *(const int4*)&csrcp[(size_t)n * CAP + 4 * j];
    #pragma unroll
    for (int k = 0; k < CAP; ++k)
        if (k >= deg) a[k] = 0x7fffffff;
    #pragma unroll
    for (int k = 2; k <= CAP; k <<= 1) {
        #pragma unroll
        for (int j = k >> 1; j > 0; j >>= 1) {
            #pragma unroll
            for (int i = 0; i < CAP; ++i) {
                const int l = i ^ j;
                if (l > i) {
                    const bool dir = ((i & k) == 0);
                    int x = a[i], y = a[l];
                    if ((x > y) == dir) { a[i] = y; a[l] = x; }
                }
            }
        }
    }
    #pragma unroll
    for (int j = 0; j < CAP / 4; ++j)
        *(int4*)&csrcp[(size_t)n * CAP + 4 * j] =
            make_int4(a[4 * j], a[4 * j + 1], a[4 * j + 2], a[4 * j + 3]);
}

// ---------------------------------------------------------------------------
// FUSED gather + MFMA conv GEMM (bf16 hi/lo split, 3-product):
//   out = relu( (feat.*gate) @ W0 + agg(feat.*gate) @ W1 + bias )
//   sun[row] = out[row,:].pvec
// 512 blocks (128 graphs x 4 row-chunks, XCD-swizzled). 512 thr = 8 waves,
// each 32x64 via 2x4 MFMA tiles. Round-16 change: phase-1's gather is
// HOISTED out of the chunk loop -- each thread accumulates its full 32-k
// aggregate slice in registers up front (8 independent float4 loads per
// neighbor, ~8x the memory-level parallelism, 1 gather pass instead of 4
// barrier-separated ones). Per-(node,k) summation order unchanged (sorted
// neighbors) -> bit-identical output. +32 VGPR; spill tripwire: WRITE>34MB.
// ---------------------------------------------------------------------------
__global__ __launch_bounds__(512, 4) void k_fgemm(const float* __restrict__ feat,
                                                  const float* __restrict__ gate,
                                                  const int* __restrict__ ccnt,
                                                  const int* __restrict__ csrcp,
                                                  const unsigned short* __restrict__ W0t,
                                                  const unsigned short* __restrict__ W1t,
                                                  const float* __restrict__ bias,
                                                  const float* __restrict__ pvec,
                                                  float* __restrict__ out,
                                                  float* __restrict__ sun) {
    __shared__ unsigned short AsBuf[2 * 128 * AST];    // AsH | AsL (18 KB)
    __shared__ unsigned short BsH[128 * AST], BsL[128 * AST];
    __shared__ unsigned short lidx[128 * LST];         // 8.4 KB
    __shared__ float lwk[128 * LST];                   // 16.9 KB
    __shared__ int ldeg[128];
    unsigned short* AsH = AsBuf;
    unsigned short* AsL = AsBuf + 128 * AST;
    float* red = (float*)AsBuf;                        // aliased epilogue buffer
    const int bid = blockIdx.x;
    const int xcd = bid & 7, j = bid >> 3;             // j: 0..63
    const int g = (j & 15) * 8 + xcd;                  // graph, fixed per xcd
    const int chunkRow = j >> 4;                       // 0..3
    const int r0 = g * N + chunkRow * 128;
    const int t = threadIdx.x;
    const int w = t >> 6, lane = t & 63;
    const int lr = lane & 15, kg = (lane >> 4) * 8;
    const int wm = (w >> 1) * 32, wn = (w & 1) * 64;   // wave tile 32x64
    const int arow = t >> 2, kpart = (t & 3) * 8;      // staging: 4 thr/row
    const int node = r0 + arow;
    const float ga = gate ? gate[node] : 1.0f;

    // --- stage neighbor lists once: thread (arow, q) owns slots q*8..q*8+7
    {
        const int q = t & 3;
        const int deg = min(ccnt[node], CAP);
        if (q == 0) ldeg[arow] = deg;
        int4 i0 = *(const int4*)&csrcp[(size_t)node * CAP + q * 8];
        int4 i1 = *(const int4*)&csrcp[(size_t)node * CAP + q * 8 + 4];
        int ids[8] = {i0.x, i0.y, i0.z, i0.w, i1.x, i1.y, i1.z, i1.w};
        #pragma unroll
        for (int u = 0; u < 8; ++u) {
            const int slot = q * 8 + u;
            lidx[arow * LST + slot] = (unsigned short)ids[u];
            float wv = 0.f;
            if (slot < deg) wv = gate ? gate[ids[u]] : 1.0f;
            lwk[arow * LST + slot] = wv;
        }
    }
    __syncthreads();

    // --- HOISTED phase-1 gather: full 32-k aggregate slice in registers.
    // Per neighbor: 8 independent float4 loads (4 thr/row cover the full
    // 512B row). Neighbor loop in sorted order -> deterministic.
    float agg[32];
    #pragma unroll
    for (int u = 0; u < 32; ++u) agg[u] = 0.f;
    {
        const int deg = ldeg[arow];
        for (int k = 0; k < deg; ++k) {
            const int ix = lidx[arow * LST + k];
            const float wv = lwk[arow * LST + k];
            const float* fp = &feat[(size_t)ix * D + kpart];
            #pragma unroll
            for (int c = 0; c < 4; ++c) {
                float4 v0 = *(const float4*)&fp[c * 32];
                float4 v1 = *(const float4*)&fp[c * 32 + 4];
                agg[c * 8 + 0] = fmaf(v0.x, wv, agg[c * 8 + 0]);
                agg[c * 8 + 1] = fmaf(v0.y, wv, agg[c * 8 + 1]);
                agg[c * 8 + 2] = fmaf(v0.z, wv, agg[c * 8 + 2]);
                agg[c * 8 + 3] = fmaf(v0.w, wv, agg[c * 8 + 3]);
                agg[c * 8 + 4] = fmaf(v1.x, wv, agg[c * 8 + 4]);
                agg[c * 8 + 5] = fmaf(v1.y, wv, agg[c * 8 + 5]);
                agg[c * 8 + 6] = fmaf(v1.z, wv, agg[c * 8 + 6]);
                agg[c * 8 + 7] = fmaf(v1.w, wv, agg[c * 8 + 7]);
            }
        }
    }

    f32x4 acc[2][4];
    #pragma unroll
    for (int mt = 0; mt < 2; ++mt)
        #pragma unroll
        for (int nt = 0; nt < 4; ++nt)
            acc[mt][nt] = (f32x4)(0.f);

    for (int phase = 0; phase < 2; ++phase) {
        const unsigned short* WH = phase ? W1t : W0t;
        const unsigned short* WL = WH + 16384;
        for (int c = 0; c < 4; ++c) {
            const int k0 = c * 32;
            __syncthreads();                 // previous chunk fully consumed
            // --- A source: 8 fp32 for (row=arow, k=k0+kpart..+8)
            float vals[8];
            if (phase == 0) {
                float4 a0 = *(const float4*)&feat[(size_t)node * D + k0 + kpart];
                float4 a1 = *(const float4*)&feat[(size_t)node * D + k0 + kpart + 4];
                vals[0] = a0.x * ga; vals[1] = a0.y * ga; vals[2] = a0.z * ga; vals[3] = a0.w * ga;
                vals[4] = a1.x * ga; vals[5] = a1.y * ga; vals[6] = a1.z * ga; vals[7] = a1.w * ga;
            } else {
                #pragma unroll
                for (int u = 0; u < 8; ++u) vals[u] = agg[c * 8 + u];
            }
            // --- split to hi/lo bf16, write LDS [row][k] stride 36 (2x int2)
            {
                unsigned int ph[4], pl[4];
                #pragma unroll
                for (int jj = 0; jj < 4; ++jj) {
                    unsigned int h0 = f2bf(vals[2 * jj]), h1 = f2bf(vals[2 * jj + 1]);
                    ph[jj] = h0 | (h1 << 16);
                    unsigned int l0 = f2bf(vals[2 * jj] - bf2f((unsigned short)h0));
                    unsigned int l1 = f2bf(vals[2 * jj + 1] - bf2f((unsigned short)h1));
                    pl[jj] = l0 | (l1 << 16);
                }
                *(int2*)&AsH[arow * AST + kpart]     = make_int2(ph[0], ph[1]);
                *(int2*)&AsH[arow * AST + kpart + 4] = make_int2(ph[2], ph[3]);
                *(int2*)&AsL[arow * AST + kpart]     = make_int2(pl[0], pl[1]);
                *(int2*)&AsL[arow * AST + kpart + 4] = make_int2(pl[2], pl[3]);
            }
            // --- B stage: copy pre-split W^T[n][k] chunk
            {
                int4 bh = *(const int4*)&WH[arow * 128 + k0 + kpart];
                int4 bl = *(const int4*)&WL[arow * 128 + k0 + kpart];
                *(int2*)&BsH[arow * AST + kpart]     = make_int2(bh.x, bh.y);
                *(int2*)&BsH[arow * AST + kpart + 4] = make_int2(bh.z, bh.w);
                *(int2*)&BsL[arow * AST + kpart]     = make_int2(bl.x, bl.y);
                *(int2*)&BsL[arow * AST + kpart + 4] = make_int2(bl.z, bl.w);
            }
            __syncthreads();
            // --- fragments (2x b64 each) + MFMA
            short8 aH[2], aL[2], bH[4], bL[4];
            #pragma unroll
            for (int mt = 0; mt < 2; ++mt) {
                const int ra = (wm + mt * 16 + lr) * AST + kg;
                ((int2*)&aH[mt])[0] = *(const int2*)&AsH[ra];
                ((int2*)&aH[mt])[1] = *(const int2*)&AsH[ra + 4];
                ((int2*)&aL[mt])[0] = *(const int2*)&AsL[ra];
                ((int2*)&aL[mt])[1] = *(const int2*)&AsL[ra + 4];
            }
            #pragma unroll
            for (int nt = 0; nt < 4; ++nt) {
                const int rb = (wn + nt * 16 + lr) * AST + kg;
                ((int2*)&bH[nt])[0] = *(const int2*)&BsH[rb];
                ((int2*)&bH[nt])[1] = *(const int2*)&BsH[rb + 4];
                ((int2*)&bL[nt])[0] = *(const int2*)&BsL[rb];
                ((int2*)&bL[nt])[1] = *(const int2*)&BsL[rb + 4];
            }
            #pragma unroll
            for (int mt = 0; mt < 2; ++mt)
                #pragma unroll
                for (int nt = 0; nt < 4; ++nt) {
                    acc[mt][nt] = __builtin_amdgcn_mfma_f32_16x16x32_bf16(aH[mt], bH[nt], acc[mt][nt], 0, 0, 0);
                    acc[mt][nt] = __builtin_amdgcn_mfma_f32_16x16x32_bf16(aH[mt], bL[nt], acc[mt][nt], 0, 0, 0);
                    acc[mt][nt] = __builtin_amdgcn_mfma_f32_16x16x32_bf16(aL[mt], bH[nt], acc[mt][nt], 0, 0, 0);
                }
        }
    }
    __syncthreads();                          // A staging dead -> red may alias
    // --- Epilogue: bias + relu + store + score partials
    float bb[4], pv[4];
    #pragma unroll
    for (int nt = 0; nt < 4; ++nt) {
        bb[nt] = bias[wn + nt * 16 + lr];
        pv[nt] = pvec[wn + nt * 16 + lr];
    }
    #pragma unroll
    for (int mt = 0; mt < 2; ++mt) {
        #pragma unroll
        for (int r = 0; r < 4; ++r) {
            const int rowl = wm + mt * 16 + (lane >> 4) * 4 + r;
            const int row = r0 + rowl;
            float part = 0.f;
            #pragma unroll
            for (int nt = 0; nt < 4; ++nt) {
                float v = acc[mt][nt][r] + bb[nt];
                v = fmaxf(v, 0.f);
                out[(size_t)row * D + wn + nt * 16 + lr] = v;
                part = fmaf(v, pv[nt], part);
            }
            red[rowl * 33 + (w & 1) * 16 + lr] = part;   // unique slot per lane
        }
    }
    __syncthreads();
    if (t < 128) {
        float s = 0.f;
        #pragma unroll
        for (int jj = 0; jj < 32; ++jj) s += red[t * 33 + jj];
        sun[r0 + t] = s;
    }
}

// ---------------------------------------------------------------------------
// Fused per-graph TopK + readout, 2 blocks per graph (feature halves).
// ---------------------------------------------------------------------------
__global__ __launch_bounds__(1024) void k_topk_readout(const float* __restrict__ sun,
                                                       const float* __restrict__ p,
                                                       const float* __restrict__ prevmask,
                                                       int K, float invK,
                                                       const float* __restrict__ h,
                                                       float* __restrict__ gate,
                                                       float* __restrict__ mask,
                                                       float* __restrict__ xout) {
    __shared__ float ls[512];
    __shared__ float lg[512];
    __shared__ float lm[512];
    __shared__ float red[128];
    __shared__ float smax[16][64];
    __shared__ float ssum[16][64];
    __shared__ float norm_s;
    const int bid = blockIdx.x;
    const int g = bid >> 1, half = bid & 1;
    const int t = threadIdx.x;
    if (t < 512) {
        const int n = g * N + t;
        float s = sun[n];
        if (prevmask && prevmask[n] == 0.0f) s = -INFINITY;
        ls[t] = s;
    }
    if (t < 128) { float pvv = p[t]; red[t] = pvv * pvv; }
    __syncthreads();
    if (t < 64) red[t] += red[t + 64];
    __syncthreads();
    if (t < 32) red[t] += red[t + 32];
    __syncthreads();
    if (t == 0) {
        float s = 0.f;
        #pragma unroll
        for (int i = 0; i < 32; ++i) s += red[i];
        norm_s = sqrtf(s);
    }
    __syncthreads();
    if (t < 512) {
        const float s = ls[t];
        int cnt = 0;
        for (int jj = 0; jj < 512; ++jj) {
            float sj = ls[jj];
            cnt += (sj > s || (sj == s && jj < t)) ? 1 : 0;
        }
        const bool keep = cnt < K;
        const float gv = keep ? tanhf(s / norm_s) : 0.0f;
        const float mv = keep ? 1.0f : 0.0f;
        lg[t] = gv; lm[t] = mv;
        gate[g * N + t] = gv; mask[g * N + t] = mv;
    }
    __syncthreads();
    const int f = half * 64 + (t & 63), sub = t >> 6;   // 16 subsets x 64 feats
    float vmax = -INFINITY, vsum = 0.f;
    for (int nl = sub; nl < N; nl += 16) {
        const float v = h[(size_t)(g * N + nl) * D + f] * lg[nl];
        vsum += v;
        if (lm[nl] != 0.f) vmax = fmaxf(vmax, v);
    }
    smax[sub][t & 63] = vmax;
    ssum[sub][t & 63] = vsum;
    __syncthreads();
    if (t < 64) {
        float m = smax[0][t], s = ssum[0][t];
        #pragma unroll
        for (int k = 1; k < 16; ++k) { m = fmaxf(m, smax[k][t]); s += ssum[k][t]; }
        xout[g * 256 + half * 64 + t] = m;
        xout[g * 256 + 128 + half * 64 + t] = s * invK;
    }
}

// ---------------------------------------------------------------------------
// MLP head. One block (128 threads) per graph.
// ---------------------------------------------------------------------------
__global__ __launch_bounds__(128) void k_mlp(const float* __restrict__ X1,
                                             const float* __restrict__ X2,
                                             const float* __restrict__ lw1,
                                             const float* __restrict__ lb1,
                                             const float* __restrict__ lw2,
                                             const float* __restrict__ lb2,
                                             const float* __restrict__ lw3,
                                             const float* __restrict__ lb3,
                                             float* __restrict__ out) {
    __shared__ float z[256];
    __shared__ float o1[128];
    __shared__ float o2p[64];
    const int g = blockIdx.x, t = threadIdx.x;
    z[t] = X1[g * 256 + t] + X2[g * 256 + t];
    z[t + 128] = X1[g * 256 + 128 + t] + X2[g * 256 + 128 + t];
    __syncthreads();
    float a = lb1[t];
    for (int i = 0; i < 256; ++i) a = fmaf(z[i], lw1[i * 128 + t], a);
    o1[t] = fmaxf(a, 0.f);
    __syncthreads();
    if (t < 64) {
        float b = lb2[t];
        for (int i = 0; i < 128; ++i) b = fmaf(o1[i], lw2[i * 64 + t], b);
        o2p[t] = fmaxf(b, 0.f) * lw3[t];
    }
    __syncthreads();
    if (t == 0) {
        float sacc = lb3[0];
        for (int i = 0; i < 64; ++i) sacc += o2p[i];
        out[g] = 1.f / (1.f + expf(-sacc));
    }
}

// ---------------------------------------------------------------------------
extern "C" void kernel_launch(void* const* d_in, const int* in_sizes, int n_in,
                              void* d_out, int out_size, void* d_ws, size_t ws_size,
                              hipStream_t stream) {
    const float* x    = (const float*)d_in[0];
    const int*   ei   = (const int*)d_in[1];
    const float* W1r  = (const float*)d_in[2];
    const float* W1n  = (const float*)d_in[3];
    const float* b1   = (const float*)d_in[4];
    const float* p1   = (const float*)d_in[5];
    const float* W2r  = (const float*)d_in[6];
    const float* W2n  = (const float*)d_in[7];
    const float* b2   = (const float*)d_in[8];
    const float* p2   = (const float*)d_in[9];
    const float* lw1  = (const float*)d_in[10];
    const float* lb1  = (const float*)d_in[11];
    const float* lw2  = (const float*)d_in[12];
    const float* lb2  = (const float*)d_in[13];
    const float* lw3  = (const float*)d_in[14];
    const float* lb3  = (const float*)d_in[15];
    float* out = (float*)d_out;

    // Workspace layout (~78 MB total)
    char* w = (char*)d_ws;
    float* h1  = (float*)w; w += (size_t)NN * D * 4;
    float* h2  = (float*)w; w += (size_t)NN * D * 4;
    int* ccnt  = (int*)w;   w += (size_t)NN * 4;
    int* csrcp = (int*)w;   w += (size_t)NN * CAP * 4;      // 8 MB
    unsigned short* wt = (unsigned short*)w; w += (size_t)4 * 2 * 16384 * 2;  // 4 mats x hi/lo
    float* sun = (float*)w; w += (size_t)NN * 4;
    float* g1  = (float*)w; w += (size_t)NN * 4;
    float* m1  = (float*)w; w += (size_t)NN * 4;
    float* g2  = (float*)w; w += (size_t)NN * 4;
    float* m2  = (float*)w; w += (size_t)NN * 4;
    float* X1  = (float*)w; w += (size_t)B * 256 * 4;
    float* X2  = (float*)w; w += (size_t)B * 256 * 4;

    const unsigned short* wt1r = wt;                 // slot 0: W1r
    const unsigned short* wt1n = wt + 1 * 32768;     // slot 1: W1n
    const unsigned short* wt2r = wt + 2 * 32768;     // slot 2: W2r
    const unsigned short* wt2n = wt + 3 * 32768;     // slot 3: W2n

    // One-time prep: tiled weight transpose (+ ccnt zeroing), edge scatter,
    // canonical sort
    k_prepw<<<64, 256, 0, stream>>>(W1r, W1n, W2r, W2n, wt, ccnt);
    k_count<<<E / 256, 256, 0, stream>>>(ei, ccnt, csrcp);
    k_sortpad<<<NN / 256, 256, 0, stream>>>(ccnt, csrcp);

    // conv1: h1 = relu(x@W1r + agg(x)@W1n + b1); s1 = h1.p1
    k_fgemm<<<512, 512, 0, stream>>>(x, nullptr, ccnt, csrcp, wt1r, wt1n, b1, p1, h1, sun);
    k_topk_readout<<<2 * B, 1024, 0, stream>>>(sun, p1, nullptr, K1, 1.0f / (float)K1, h1, g1, m1, X1);

    // conv2: h2 = relu((h1.*g1)@W2r + agg(h1.*g1)@W2n + b2); s2 = h2.p2
    k_fgemm<<<512, 512, 0, stream>>>(h1, g1, ccnt, csrcp, wt2r, wt2n, b2, p2, h2, sun);
    k_topk_readout<<<2 * B, 1024, 0, stream>>>(sun, p2, m1, K2, 1.0f / (float)K2, h2, g2, m2, X2);

    // MLP head
    k_mlp<<<B, 128, 0, stream>>>(X1, X2, lw1, lb1, lw2, lb2, lw3, lb3, out);
}